// Round 3
// baseline (226.479 us; speedup 1.0000x reference)
//
#include <hip/hip_runtime.h>
#include <hip/hip_bf16.h>
#include <cstdint>

#define NN    1024
#define MM    32
#define NEDGE 32240
#define MROWS 64480   // 2*NEDGE

typedef unsigned short ushort_t;

typedef __bf16 bf16x8 __attribute__((ext_vector_type(8)));
typedef float  floatx4 __attribute__((ext_vector_type(4)));

__device__ __forceinline__ float b2f(ushort_t u) {
    union { unsigned int i; float f; } v; v.i = ((unsigned int)u) << 16; return v.f;
}
__device__ __forceinline__ ushort_t f2b(float f) {
    unsigned int u = __builtin_bit_cast(unsigned int, f);
    u = (u + 0x7FFFu + ((u >> 16) & 1u)) >> 16;
    return (ushort_t)u;
}
// K(i): number of edges before node i
__device__ __forceinline__ int edge_base(int i) {
    return (i <= MM) ? ((i * (i - 1)) >> 1) : (496 + (i - MM) * MM);
}

// ---------------- weight pack (fp32 -> bf16): Wp[n*K + k] = W[k*N + n] ----------------
__global__ void k_pack(const float* an1, const float* an2, const float* ae1,
                       const float* ae2, const float* le1, const float* le2,
                       ushort_t* pan1, ushort_t* pan2, ushort_t* pae1,
                       ushort_t* pae2, ushort_t* ple1, ushort_t* ple2) {
    int idx = blockIdx.x * 256 + threadIdx.x;   // 0..106495 exactly
    const float* s; ushort_t* d; int K, N, off;
    if (idx < 40960)       { s = an1; d = pan1; K = 160; N = 256; off = idx;          }
    else if (idx < 73728)  { s = an2; d = pan2; K = 256; N = 128; off = idx - 40960;  }
    else if (idx < 86016)  { s = ae1; d = pae1; K = 96;  N = 128; off = idx - 73728;  }
    else if (idx < 94208)  { s = ae2; d = pae2; K = 128; N = 64;  off = idx - 86016;  }
    else if (idx < 103424) { s = le1; d = ple1; K = 96;  N = 96;  off = idx - 94208;  }
    else                   { s = le2; d = ple2; K = 96;  N = 32;  off = idx - 103424; }
    int n = off / K, k = off - n * K;
    d[off] = f2b(s[k * N + n]);
}

// ---------------- gather X[r, 0:160] = bf16([nodes[j] | edge[e] | nodes[i]]), pitch 168 ----------------
__global__ void k_gather(const float* __restrict__ nodes, const float* __restrict__ edges,
                         ushort_t* __restrict__ X) {
    int wid = (blockIdx.x * blockDim.x + threadIdx.x) >> 6;   // row = wave
    int l = threadIdx.x & 63;
    if (wid >= MROWS) return;
    int b = (wid >= NEDGE) ? 1 : 0;
    int e = wid - b * NEDGE;
    int i, p, j;
    if (e < 496) {
        i = (int)((1.0f + sqrtf(8.0f * (float)e + 1.0f)) * 0.5f);
        while (((i * (i - 1)) >> 1) > e) --i;
        while (((i * (i + 1)) >> 1) <= e) ++i;
        p = e - ((i * (i - 1)) >> 1);
        j = p;
    } else {
        int q = e - 496;
        i = MM + (q >> 5);
        p = q & 31;
        j = i - MM + p;
    }
    (void)p;
    ushort_t* xr = X + (size_t)wid * 168;
    const float* nj = nodes + (size_t)(b * NN + j) * 64;
    const float* ni = nodes + (size_t)(b * NN + i) * 64;
    const float* ee = edges + (size_t)wid * 32;
    xr[l]      = f2b(nj[l]);
    xr[96 + l] = f2b(ni[l]);
    if (l < 32) xr[64 + l] = f2b(ee[l]);
}

// ---------------- generic MFMA GEMM: out = relu(in[:, :KT*32] @ W + bias) ----------------
// in: bf16 row-major, pitch PIN, rows tiled by 32 (tile = contiguous TILEB bytes).
// wp: packed bf16 [Ntot][K]. bias fp32. Wave w handles NT n-tiles of 16 at n0 = w*NT*16.
// F32OUT: write fp32 (final output) vs bf16 (intermediate).
template<int KT, int NT, int WAVES, int PIN, bool F32OUT>
__global__ void k_gemm(const ushort_t* __restrict__ in, const ushort_t* __restrict__ wp,
                       const float* __restrict__ bias, void* __restrict__ out,
                       int outPitch, int mtiles) {
    constexpr int K = KT * 32;
    constexpr int TILEB = 32 * PIN * 2;        // bytes per 32-row tile
    constexpr int CHUNKS = TILEB / 16;         // PIN even -> exact
    __shared__ alignas(16) unsigned char lds[TILEB];

    const int tid = threadIdx.x;
    const int w = tid >> 6;
    const int l = tid & 63;
    const int lrow = l & 15;
    const int lq = l >> 4;
    const int n0 = w * (NT * 16);

    // hoist B fragments + bias into registers (reused for all M-tiles)
    bf16x8 bfr[KT][NT];
#pragma unroll
    for (int kt = 0; kt < KT; ++kt)
#pragma unroll
        for (int nt = 0; nt < NT; ++nt) {
            const uint4* src = (const uint4*)(wp + (size_t)(n0 + nt * 16 + lrow) * K + kt * 32 + lq * 8);
            bfr[kt][nt] = __builtin_bit_cast(bf16x8, *src);
        }
    float bv[NT];
#pragma unroll
    for (int nt = 0; nt < NT; ++nt) bv[nt] = bias[n0 + nt * 16 + lrow];

    for (int mt = blockIdx.x; mt < mtiles; mt += gridDim.x) {
        const uint4* src = (const uint4*)(in + (size_t)mt * 32 * PIN);
        uint4* dst = (uint4*)lds;
        for (int c = tid; c < CHUNKS; c += WAVES * 64) {
            dst[c] = src[c];
        }
        __syncthreads();

        floatx4 acc[2][NT];
        floatx4 zero = {0.f, 0.f, 0.f, 0.f};
#pragma unroll
        for (int s = 0; s < 2; ++s)
#pragma unroll
            for (int nt = 0; nt < NT; ++nt) acc[s][nt] = zero;

#pragma unroll
        for (int s = 0; s < 2; ++s) {
#pragma unroll
            for (int kt = 0; kt < KT; ++kt) {
                const uint4* ap = (const uint4*)&lds[(s * 16 + lrow) * (PIN * 2) + kt * 64 + lq * 16];
                bf16x8 a = __builtin_bit_cast(bf16x8, *ap);
#pragma unroll
                for (int nt = 0; nt < NT; ++nt)
                    acc[s][nt] = __builtin_amdgcn_mfma_f32_16x16x32_bf16(a, bfr[kt][nt], acc[s][nt], 0, 0, 0);
            }
        }

#pragma unroll
        for (int s = 0; s < 2; ++s)
#pragma unroll
            for (int nt = 0; nt < NT; ++nt) {
                int col = n0 + nt * 16 + lrow;
                int r0 = mt * 32 + s * 16 + lq * 4;
#pragma unroll
                for (int r = 0; r < 4; ++r) {
                    float v = fmaxf(acc[s][nt][r] + bv[nt], 0.f);
                    if (F32OUT) ((float*)out)[(size_t)(r0 + r) * outPitch + col] = v;
                    else        ((ushort_t*)out)[(size_t)(r0 + r) * outPitch + col] = f2b(v);
                }
            }
        __syncthreads();
    }
}

// ---------------- node finalize: pn = mean(hn over window); out_nodes = MLP2([pn, x_i]) ----------------
__global__ void k_node_final(const ushort_t* __restrict__ hn, const float* __restrict__ nodes,
                             const float* __restrict__ W1, const float* __restrict__ b1,
                             const float* __restrict__ W2, const float* __restrict__ b2,
                             float* __restrict__ outp) {
    int bi = blockIdx.x;                  // 0..2047
    int b = bi >> 10, i = bi & 1023;
    int t = min(i, MM);
    int base = edge_base(i);
    __shared__ float xin[192];
    __shared__ float h[192];
    int tid = threadIdx.x;                // 192 threads
    if (tid < 128) {
        float s = 0.f;
        const ushort_t* hp = hn + (size_t)(b * NEDGE + base) * 136 + tid;
        for (int p = 0; p < t; ++p) s += b2f(hp[(size_t)p * 136]);
        xin[tid] = s * (1.0f / (float)max(t, 1));
    } else {
        xin[tid] = nodes[(size_t)(b * NN + i) * 64 + (tid - 128)];
    }
    __syncthreads();
    {
        float a = b1[tid];
        const float* wc = W1 + tid;
        for (int k = 0; k < 192; ++k) a += xin[k] * wc[(size_t)k * 192];
        h[tid] = fmaxf(a, 0.f);
    }
    __syncthreads();
    if (tid < 64) {
        float a = b2[tid];
        const float* wc = W2 + tid;
        for (int k = 0; k < 192; ++k) a += h[k] * wc[(size_t)k * 64];
        outp[(size_t)(b * NN + i) * 64 + tid] = fmaxf(a, 0.f);
    }
}

// ---------------- edge prefix: ein[e] = bf16([prefix-mean(he), input_edge]), pitch 104 ----------------
__global__ void k_edge_prefix(const ushort_t* __restrict__ he, const float* __restrict__ edges,
                              ushort_t* __restrict__ ein) {
    int bi = blockIdx.x;
    int b = bi >> 10, i = bi & 1023;
    int t = min(i, MM);
    if (t == 0) return;
    int base = b * NEDGE + edge_base(i);
    int tid = threadIdx.x;                // 128 threads
    if (tid < 64) {
        float run = 0.f;
        for (int p = 0; p < t; ++p) {
            float v = (p == 0) ? 0.f : run / (float)p;
            ein[(size_t)(base + p) * 104 + tid] = f2b(v);
            run += b2f(he[(size_t)(base + p) * 72 + tid]);
        }
    } else if (tid < 96) {
        int c = tid - 64;
        for (int p = 0; p < t; ++p)
            ein[(size_t)(base + p) * 104 + 64 + c] = f2b(edges[(size_t)(base + p) * 32 + c]);
    }
}

extern "C" void kernel_launch(void* const* d_in, const int* in_sizes, int n_in,
                              void* d_out, int out_size, void* d_ws, size_t ws_size,
                              hipStream_t stream) {
    const float* nodes = (const float*)d_in[0];
    const float* edges = (const float*)d_in[1];
    const float* Wan1 = (const float*)d_in[2];  const float* ban1 = (const float*)d_in[3];
    const float* Wan2 = (const float*)d_in[4];  const float* ban2 = (const float*)d_in[5];
    const float* Wln1 = (const float*)d_in[6];  const float* bln1 = (const float*)d_in[7];
    const float* Wln2 = (const float*)d_in[8];  const float* bln2 = (const float*)d_in[9];
    const float* Wae1 = (const float*)d_in[10]; const float* bae1 = (const float*)d_in[11];
    const float* Wae2 = (const float*)d_in[12]; const float* bae2 = (const float*)d_in[13];
    const float* Wle1 = (const float*)d_in[14]; const float* ble1 = (const float*)d_in[15];
    const float* Wle2 = (const float*)d_in[16]; const float* ble2 = (const float*)d_in[17];

    char* ws = (char*)d_ws;
    size_t o = 0;
    auto alloc = [&](size_t bytes) -> void* {
        void* r = ws + o;
        o += (bytes + 255) & ~(size_t)255;
        return r;
    };
    ushort_t* X    = (ushort_t*)alloc((size_t)MROWS * 168 * 2);
    ushort_t* H1n  = (ushort_t*)alloc((size_t)MROWS * 264 * 2);
    ushort_t* hn   = (ushort_t*)alloc((size_t)MROWS * 136 * 2);
    ushort_t* pan1 = (ushort_t*)alloc(160 * 256 * 2);
    ushort_t* pan2 = (ushort_t*)alloc(256 * 128 * 2);
    ushort_t* pae1 = (ushort_t*)alloc(96 * 128 * 2);
    ushort_t* pae2 = (ushort_t*)alloc(128 * 64 * 2);
    ushort_t* ple1 = (ushort_t*)alloc(96 * 96 * 2);
    ushort_t* ple2 = (ushort_t*)alloc(96 * 32 * 2);
    // aliases (lifetimes are disjoint in stream order):
    ushort_t* H1e = H1n;   // H1e [MROWS,136] written (launch 5) after H1n's last read (launch 4)
    ushort_t* he  = X;     // he [MROWS,72] written (launch 6) after X's last read (launch 5)
    ushort_t* ein = hn;    // ein [MROWS,104] written (launch 8) after hn's last read (launch 7)
    ushort_t* Hf  = H1n;   // Hf [MROWS,96/104] written (launch 9) after H1e's last read (launch 6)

    float* out_nodes = (float*)d_out;
    float* out_edges = (float*)d_out + 2 * NN * 64;

    k_pack<<<416, 256, 0, stream>>>(Wan1, Wan2, Wae1, Wae2, Wle1, Wle2,
                                    pan1, pan2, pae1, pae2, ple1, ple2);
    k_gather<<<(MROWS + 3) / 4, 256, 0, stream>>>(nodes, edges, X);

    // node branch: X[:, :160] @ Wan1 -> H1n [.,256] ; H1n @ Wan2 -> hn [.,128]
    k_gemm<5, 4, 4, 168, false><<<2015, 256, 0, stream>>>(X,   pan1, ban1, H1n, 264, 2015);
    k_gemm<8, 2, 4, 264, false><<<2015, 256, 0, stream>>>(H1n, pan2, ban2, hn,  136, 2015);
    // edge branch: X[:, :96] @ Wae1 -> H1e [.,128] ; H1e @ Wae2 -> he [.,64]
    k_gemm<3, 2, 4, 168, false><<<2015, 256, 0, stream>>>(X,   pae1, bae1, H1e, 136, 2015);
    k_gemm<4, 1, 4, 136, false><<<2015, 256, 0, stream>>>(H1e, pae2, bae2, he,  72,  2015);
    // node finalize (consumes hn; must precede ein alias write)
    k_node_final<<<2048, 192, 0, stream>>>(hn, nodes, Wln1, bln1, Wln2, bln2, out_nodes);
    // edge finalize
    k_edge_prefix<<<2048, 128, 0, stream>>>(he, edges, ein);
    k_gemm<3, 2, 3, 104, false><<<2015, 192, 0, stream>>>(ein, ple1, ble1, Hf, 104, 2015);
    k_gemm<3, 1, 2, 104, true><<<2015, 128, 0, stream>>>(Hf,  ple2, ble2, out_edges, 32, 2015);

    (void)in_sizes; (void)n_in; (void)out_size; (void)ws_size;
}

// Round 4
// 218.769 us; speedup vs baseline: 1.0352x; 1.0352x over previous
//
#include <hip/hip_runtime.h>
#include <cstdint>

#define NN    1024
#define MM    32
#define NEDGE 32240
#define MROWS 64480   // 2*NEDGE

typedef unsigned short ushort_t;

typedef __bf16 bf16x8 __attribute__((ext_vector_type(8)));
typedef float  floatx4 __attribute__((ext_vector_type(4)));

__device__ __forceinline__ float b2f(ushort_t u) {
    union { unsigned int i; float f; } v; v.i = ((unsigned int)u) << 16; return v.f;
}
__device__ __forceinline__ ushort_t f2b(float f) {
    unsigned int u = __builtin_bit_cast(unsigned int, f);
    u = (u + 0x7FFFu + ((u >> 16) & 1u)) >> 16;
    return (ushort_t)u;
}
// K(i): number of edges before node i
__device__ __forceinline__ int edge_base(int i) {
    return (i <= MM) ? ((i * (i - 1)) >> 1) : (496 + (i - MM) * MM);
}
// edge id e -> (dest i, src j)   [validated in round 3]
__device__ __forceinline__ void edge_ij(int e, int& i, int& j) {
    if (e < 496) {
        i = (int)((1.0f + sqrtf(8.0f * (float)e + 1.0f)) * 0.5f);
        while (((i * (i - 1)) >> 1) > e) --i;
        while (((i * (i + 1)) >> 1) <= e) ++i;
        j = e - ((i * (i - 1)) >> 1);
    } else {
        int q = e - 496;
        i = MM + (q >> 5);
        j = i - MM + (q & 31);
    }
}

// ---------------- weight pack (fp32 -> bf16 transpose): Wp[n*K + k] = W[k*N + n] ----------------
__global__ void k_pack(const float* an1, const float* an2, const float* ae1,
                       const float* ae2, const float* le1, const float* le2,
                       const float* ln1, const float* ln2,
                       ushort_t* pan1, ushort_t* pan2, ushort_t* pae1, ushort_t* pae2,
                       ushort_t* ple1, ushort_t* ple2, ushort_t* pln1, ushort_t* pln2) {
    int idx = blockIdx.x * 256 + threadIdx.x;   // 0..155647 exactly
    const float* s; ushort_t* d; int K, N, off;
    if (idx < 40960)       { s = an1; d = pan1; K = 160; N = 256; off = idx;          }
    else if (idx < 73728)  { s = an2; d = pan2; K = 256; N = 128; off = idx - 40960;  }
    else if (idx < 86016)  { s = ae1; d = pae1; K = 96;  N = 128; off = idx - 73728;  }
    else if (idx < 94208)  { s = ae2; d = pae2; K = 128; N = 64;  off = idx - 86016;  }
    else if (idx < 103424) { s = le1; d = ple1; K = 96;  N = 96;  off = idx - 94208;  }
    else if (idx < 106496) { s = le2; d = ple2; K = 96;  N = 32;  off = idx - 103424; }
    else if (idx < 143360) { s = ln1; d = pln1; K = 192; N = 192; off = idx - 106496; }
    else                   { s = ln2; d = pln2; K = 192; N = 64;  off = idx - 143360; }
    int n = off / K, k = off - n * K;
    d[off] = f2b(s[k * N + n]);
}

// ---------------- fuse1: gather + an1 (160->256) + ae1 (96->128), one 32-row tile/block ----------------
__global__ __launch_bounds__(384) void k_fuse1(
        const float* __restrict__ nodes, const float* __restrict__ edges,
        const ushort_t* __restrict__ pan1, const float* __restrict__ ban1,
        const ushort_t* __restrict__ pae1, const float* __restrict__ bae1,
        ushort_t* __restrict__ H1n, ushort_t* __restrict__ H1e) {
    __shared__ alignas(16) ushort_t xt[32 * 160];
    const int tid = threadIdx.x;
    const int w = tid >> 6, l = tid & 63, lrow = l & 15, lq = l >> 4;
    const int mt = blockIdx.x;

    // B fragments (wave-uniform path split: waves 0-3 = an1, waves 4-5 = ae1)
    bf16x8 bfr[5][4]; float bv[4];
    if (w < 4) {
        int n0 = w * 64;
#pragma unroll
        for (int kt = 0; kt < 5; ++kt)
#pragma unroll
            for (int nt = 0; nt < 4; ++nt)
                bfr[kt][nt] = *(const bf16x8*)(pan1 + (size_t)(n0 + nt * 16 + lrow) * 160 + kt * 32 + lq * 8);
#pragma unroll
        for (int nt = 0; nt < 4; ++nt) bv[nt] = ban1[n0 + nt * 16 + lrow];
    } else {
        int n0 = (w - 4) * 64;
#pragma unroll
        for (int kt = 0; kt < 3; ++kt)
#pragma unroll
            for (int nt = 0; nt < 4; ++nt)
                bfr[kt][nt] = *(const bf16x8*)(pae1 + (size_t)(n0 + nt * 16 + lrow) * 96 + kt * 32 + lq * 8);
#pragma unroll
        for (int nt = 0; nt < 4; ++nt) bv[nt] = bae1[n0 + nt * 16 + lrow];
    }

    // in-kernel gather: row = [nodes[j](64) | edge(32) | nodes[i](64)], pitch 160
    for (int rr = w; rr < 32; rr += 6) {
        int r = mt * 32 + rr;
        int b = (r >= NEDGE) ? 1 : 0;
        int e = r - b * NEDGE;
        int i, j; edge_ij(e, i, j);
        ushort_t* xr = xt + rr * 160;
        const float* nj = nodes + (size_t)(b * NN + j) * 64;
        const float* ni = nodes + (size_t)(b * NN + i) * 64;
        xr[l]      = f2b(nj[l]);
        xr[96 + l] = f2b(ni[l]);
        if (l < 32) xr[64 + l] = f2b(edges[(size_t)r * 32 + l]);
    }
    __syncthreads();

    floatx4 acc[2][4];
    floatx4 zero = {0.f, 0.f, 0.f, 0.f};
#pragma unroll
    for (int s = 0; s < 2; ++s)
#pragma unroll
        for (int nt = 0; nt < 4; ++nt) acc[s][nt] = zero;

    if (w < 4) {
#pragma unroll
        for (int s = 0; s < 2; ++s)
#pragma unroll
            for (int kt = 0; kt < 5; ++kt) {
                bf16x8 a = *(const bf16x8*)&xt[(s * 16 + lrow) * 160 + kt * 32 + lq * 8];
#pragma unroll
                for (int nt = 0; nt < 4; ++nt)
                    acc[s][nt] = __builtin_amdgcn_mfma_f32_16x16x32_bf16(a, bfr[kt][nt], acc[s][nt], 0, 0, 0);
            }
#pragma unroll
        for (int s = 0; s < 2; ++s)
#pragma unroll
            for (int nt = 0; nt < 4; ++nt) {
                int col = w * 64 + nt * 16 + lrow;
#pragma unroll
                for (int r_ = 0; r_ < 4; ++r_) {
                    int row = mt * 32 + s * 16 + lq * 4 + r_;
                    H1n[(size_t)row * 264 + col] = f2b(fmaxf(acc[s][nt][r_] + bv[nt], 0.f));
                }
            }
    } else {
#pragma unroll
        for (int s = 0; s < 2; ++s)
#pragma unroll
            for (int kt = 0; kt < 3; ++kt) {
                bf16x8 a = *(const bf16x8*)&xt[(s * 16 + lrow) * 160 + kt * 32 + lq * 8];
#pragma unroll
                for (int nt = 0; nt < 4; ++nt)
                    acc[s][nt] = __builtin_amdgcn_mfma_f32_16x16x32_bf16(a, bfr[kt][nt], acc[s][nt], 0, 0, 0);
            }
#pragma unroll
        for (int s = 0; s < 2; ++s)
#pragma unroll
            for (int nt = 0; nt < 4; ++nt) {
                int col = (w - 4) * 64 + nt * 16 + lrow;
#pragma unroll
                for (int r_ = 0; r_ < 4; ++r_) {
                    int row = mt * 32 + s * 16 + lq * 4 + r_;
                    H1e[(size_t)row * 136 + col] = f2b(fmaxf(acc[s][nt][r_] + bv[nt], 0.f));
                }
            }
    }
}

// ---------------- generic single-tile GEMM body (device) ----------------
template<int KT, int NT, int WAVES, int PIN>
__device__ __forceinline__ void gemm_block(const ushort_t* __restrict__ in,
                                           const ushort_t* __restrict__ wp,
                                           const float* __restrict__ bias,
                                           ushort_t* __restrict__ out, int outPitch,
                                           int mt, ushort_t* lds) {
    constexpr int K = KT * 32;
    constexpr int CHUNKS = 32 * PIN / 8;   // uint4 chunks per tile
    const int tid = threadIdx.x;
    const int w = tid >> 6, l = tid & 63, lrow = l & 15, lq = l >> 4;
    const int n0 = w * (NT * 16);

    bf16x8 bfr[KT][NT]; float bv[NT];
#pragma unroll
    for (int kt = 0; kt < KT; ++kt)
#pragma unroll
        for (int nt = 0; nt < NT; ++nt)
            bfr[kt][nt] = *(const bf16x8*)(wp + (size_t)(n0 + nt * 16 + lrow) * K + kt * 32 + lq * 8);
#pragma unroll
    for (int nt = 0; nt < NT; ++nt) bv[nt] = bias[n0 + nt * 16 + lrow];

    const uint4* src = (const uint4*)(in + (size_t)mt * 32 * PIN);
    uint4* dst = (uint4*)lds;
    for (int c = tid; c < CHUNKS; c += WAVES * 64) dst[c] = src[c];
    __syncthreads();

    floatx4 acc[2][NT];
    floatx4 zero = {0.f, 0.f, 0.f, 0.f};
#pragma unroll
    for (int s = 0; s < 2; ++s)
#pragma unroll
        for (int nt = 0; nt < NT; ++nt) acc[s][nt] = zero;

#pragma unroll
    for (int s = 0; s < 2; ++s)
#pragma unroll
        for (int kt = 0; kt < KT; ++kt) {
            bf16x8 a = *(const bf16x8*)&lds[(s * 16 + lrow) * PIN + kt * 32 + lq * 8];
#pragma unroll
            for (int nt = 0; nt < NT; ++nt)
                acc[s][nt] = __builtin_amdgcn_mfma_f32_16x16x32_bf16(a, bfr[kt][nt], acc[s][nt], 0, 0, 0);
        }

#pragma unroll
    for (int s = 0; s < 2; ++s)
#pragma unroll
        for (int nt = 0; nt < NT; ++nt) {
            int col = n0 + nt * 16 + lrow;
#pragma unroll
            for (int r_ = 0; r_ < 4; ++r_) {
                int row = mt * 32 + s * 16 + lq * 4 + r_;
                out[(size_t)row * outPitch + col] = f2b(fmaxf(acc[s][nt][r_] + bv[nt], 0.f));
            }
        }
}

// ---------------- fuse2: an2 (256->128) | ae2 (128->64), blockIdx split ----------------
__global__ __launch_bounds__(256) void k_fuse2(
        const ushort_t* __restrict__ H1n, const ushort_t* __restrict__ pan2,
        const float* __restrict__ ban2, ushort_t* __restrict__ hn,
        const ushort_t* __restrict__ H1e, const ushort_t* __restrict__ pae2,
        const float* __restrict__ bae2, ushort_t* __restrict__ he) {
    __shared__ alignas(16) ushort_t lds[32 * 264];
    if (blockIdx.x < 2015) {
        gemm_block<8, 2, 4, 264>(H1n, pan2, ban2, hn, 136, blockIdx.x, lds);
    } else {
        gemm_block<4, 1, 4, 136>(H1e, pae2, bae2, he, 72, blockIdx.x - 2015, lds);
    }
}

// ---------------- fuse3: node_final | edge_prefix, blockIdx split ----------------
__global__ __launch_bounds__(192) void k_fuse3(
        const ushort_t* __restrict__ hn, const float* __restrict__ nodes,
        const ushort_t* __restrict__ pln1, const float* __restrict__ bln1,
        const ushort_t* __restrict__ pln2, const float* __restrict__ bln2,
        float* __restrict__ out_nodes,
        const ushort_t* __restrict__ he, const float* __restrict__ edges,
        ushort_t* __restrict__ ein) {
    int tid = threadIdx.x;
    if (blockIdx.x < 2048) {
        // node finalize: pn = window mean of hn; out = relu(relu([pn,x]W1+b1)W2+b2)
        int bi = blockIdx.x;
        int b = bi >> 10, i = bi & 1023;
        int t = min(i, MM);
        int base = edge_base(i);
        __shared__ float xin[192];
        __shared__ float h[192];
        if (tid < 128) {
            float s = 0.f;
            const ushort_t* hp = hn + (size_t)(b * NEDGE + base) * 136 + tid;
            for (int p = 0; p < t; ++p) s += b2f(hp[(size_t)p * 136]);
            xin[tid] = s * (1.0f / (float)max(t, 1));
        } else {
            xin[tid] = nodes[(size_t)(b * NN + i) * 64 + (tid - 128)];
        }
        __syncthreads();
        {
            float a = 0.f;
            const uint4* wv = (const uint4*)(pln1 + (size_t)tid * 192);
#pragma unroll
            for (int k8 = 0; k8 < 24; ++k8) {
                uint4 u = wv[k8];
                const ushort_t* us = (const ushort_t*)&u;
#pragma unroll
                for (int jj = 0; jj < 8; ++jj) a += xin[k8 * 8 + jj] * b2f(us[jj]);
            }
            h[tid] = fmaxf(a + bln1[tid], 0.f);
        }
        __syncthreads();
        if (tid < 64) {
            float a = 0.f;
            const uint4* wv = (const uint4*)(pln2 + (size_t)tid * 192);
#pragma unroll
            for (int k8 = 0; k8 < 24; ++k8) {
                uint4 u = wv[k8];
                const ushort_t* us = (const ushort_t*)&u;
#pragma unroll
                for (int jj = 0; jj < 8; ++jj) a += h[k8 * 8 + jj] * b2f(us[jj]);
            }
            out_nodes[(size_t)(b * NN + i) * 64 + tid] = fmaxf(a + bln2[tid], 0.f);
        }
    } else {
        // edge prefix: ein[e] = [prefix-mean(he) (64) | input_edge (32)], pitch 104
        int bi = blockIdx.x - 2048;
        int b = bi >> 10, i = bi & 1023;
        int t = min(i, MM);
        if (t == 0) return;
        int base = b * NEDGE + edge_base(i);
        if (tid < 64) {
            float run = 0.f;
            for (int p = 0; p < t; ++p) {
                float v = (p == 0) ? 0.f : run / (float)p;
                ein[(size_t)(base + p) * 104 + tid] = f2b(v);
                run += b2f(he[(size_t)(base + p) * 72 + tid]);
            }
        } else if (tid < 96) {
            int c = tid - 64;
            for (int p = 0; p < t; ++p)
                ein[(size_t)(base + p) * 104 + 64 + c] = f2b(edges[(size_t)(base + p) * 32 + c]);
        }
    }
}

// ---------------- le12: le1 (96->96) -> LDS -> le2 (96->32), fused per tile ----------------
__global__ __launch_bounds__(192) void k_le12(
        const ushort_t* __restrict__ ein, const ushort_t* __restrict__ ple1,
        const float* __restrict__ ble1, const ushort_t* __restrict__ ple2,
        const float* __restrict__ ble2, float* __restrict__ out_edges) {
    __shared__ alignas(16) ushort_t tin[32 * 104];
    __shared__ alignas(16) ushort_t tmid[32 * 104];
    const int tid = threadIdx.x;
    const int w = tid >> 6, l = tid & 63, lrow = l & 15, lq = l >> 4;
    const int mt = blockIdx.x;

    {   // stage ein tile: 416 uint4 chunks
        const uint4* src = (const uint4*)(ein + (size_t)mt * 32 * 104);
        uint4* dst = (uint4*)tin;
        for (int c = tid; c < 416; c += 192) dst[c] = src[c];
    }
    // le1 B frags: 3 waves, NT=2, n0 = w*32
    bf16x8 fb1[3][2]; float v1[2];
#pragma unroll
    for (int kt = 0; kt < 3; ++kt)
#pragma unroll
        for (int nt = 0; nt < 2; ++nt)
            fb1[kt][nt] = *(const bf16x8*)(ple1 + (size_t)(w * 32 + nt * 16 + lrow) * 96 + kt * 32 + lq * 8);
#pragma unroll
    for (int nt = 0; nt < 2; ++nt) v1[nt] = ble1[w * 32 + nt * 16 + lrow];
    // le2 B frags: waves 0-1, NT=1, n0 = w*16
    bf16x8 fb2[3]; float v2 = 0.f;
    if (w < 2) {
#pragma unroll
        for (int kt = 0; kt < 3; ++kt)
            fb2[kt] = *(const bf16x8*)(ple2 + (size_t)(w * 16 + lrow) * 96 + kt * 32 + lq * 8);
        v2 = ble2[w * 16 + lrow];
    }
    __syncthreads();

    floatx4 acc[2][2];
    floatx4 zero = {0.f, 0.f, 0.f, 0.f};
#pragma unroll
    for (int s = 0; s < 2; ++s) { acc[s][0] = zero; acc[s][1] = zero; }
#pragma unroll
    for (int s = 0; s < 2; ++s)
#pragma unroll
        for (int kt = 0; kt < 3; ++kt) {
            bf16x8 a = *(const bf16x8*)&tin[(s * 16 + lrow) * 104 + kt * 32 + lq * 8];
#pragma unroll
            for (int nt = 0; nt < 2; ++nt)
                acc[s][nt] = __builtin_amdgcn_mfma_f32_16x16x32_bf16(a, fb1[kt][nt], acc[s][nt], 0, 0, 0);
        }
#pragma unroll
    for (int s = 0; s < 2; ++s)
#pragma unroll
        for (int nt = 0; nt < 2; ++nt) {
            int col = w * 32 + nt * 16 + lrow;
#pragma unroll
            for (int r_ = 0; r_ < 4; ++r_)
                tmid[(s * 16 + lq * 4 + r_) * 104 + col] = f2b(fmaxf(acc[s][nt][r_] + v1[nt], 0.f));
        }
    __syncthreads();

    if (w < 2) {
        floatx4 a2[2] = {zero, zero};
#pragma unroll
        for (int s = 0; s < 2; ++s)
#pragma unroll
            for (int kt = 0; kt < 3; ++kt) {
                bf16x8 a = *(const bf16x8*)&tmid[(s * 16 + lrow) * 104 + kt * 32 + lq * 8];
                a2[s] = __builtin_amdgcn_mfma_f32_16x16x32_bf16(a, fb2[kt], a2[s], 0, 0, 0);
            }
#pragma unroll
        for (int s = 0; s < 2; ++s) {
            int col = w * 16 + lrow;
#pragma unroll
            for (int r_ = 0; r_ < 4; ++r_) {
                int row = mt * 32 + s * 16 + lq * 4 + r_;
                out_edges[(size_t)row * 32 + col] = fmaxf(a2[s][r_] + v2, 0.f);
            }
        }
    }
}

extern "C" void kernel_launch(void* const* d_in, const int* in_sizes, int n_in,
                              void* d_out, int out_size, void* d_ws, size_t ws_size,
                              hipStream_t stream) {
    const float* nodes = (const float*)d_in[0];
    const float* edges = (const float*)d_in[1];
    const float* Wan1 = (const float*)d_in[2];  const float* ban1 = (const float*)d_in[3];
    const float* Wan2 = (const float*)d_in[4];  const float* ban2 = (const float*)d_in[5];
    const float* Wln1 = (const float*)d_in[6];  const float* bln1 = (const float*)d_in[7];
    const float* Wln2 = (const float*)d_in[8];  const float* bln2 = (const float*)d_in[9];
    const float* Wae1 = (const float*)d_in[10]; const float* bae1 = (const float*)d_in[11];
    const float* Wae2 = (const float*)d_in[12]; const float* bae2 = (const float*)d_in[13];
    const float* Wle1 = (const float*)d_in[14]; const float* ble1 = (const float*)d_in[15];
    const float* Wle2 = (const float*)d_in[16]; const float* ble2 = (const float*)d_in[17];

    char* ws = (char*)d_ws;
    size_t o = 0;
    auto alloc = [&](size_t bytes) -> void* {
        void* r = ws + o;
        o += (bytes + 255) & ~(size_t)255;
        return r;
    };
    ushort_t* H1n  = (ushort_t*)alloc((size_t)MROWS * 264 * 2);
    ushort_t* hn   = (ushort_t*)alloc((size_t)MROWS * 136 * 2);
    ushort_t* H1e  = (ushort_t*)alloc((size_t)MROWS * 136 * 2);
    ushort_t* he   = (ushort_t*)alloc((size_t)MROWS * 72 * 2);
    ushort_t* ein  = (ushort_t*)alloc((size_t)MROWS * 104 * 2);
    ushort_t* pan1 = (ushort_t*)alloc(160 * 256 * 2);
    ushort_t* pan2 = (ushort_t*)alloc(256 * 128 * 2);
    ushort_t* pae1 = (ushort_t*)alloc(96 * 128 * 2);
    ushort_t* pae2 = (ushort_t*)alloc(128 * 64 * 2);
    ushort_t* ple1 = (ushort_t*)alloc(96 * 96 * 2);
    ushort_t* ple2 = (ushort_t*)alloc(96 * 32 * 2);
    ushort_t* pln1 = (ushort_t*)alloc(192 * 192 * 2);
    ushort_t* pln2 = (ushort_t*)alloc(192 * 64 * 2);

    float* out_nodes = (float*)d_out;
    float* out_edges = (float*)d_out + 2 * NN * 64;

    k_pack<<<608, 256, 0, stream>>>(Wan1, Wan2, Wae1, Wae2, Wle1, Wle2, Wln1, Wln2,
                                    pan1, pan2, pae1, pae2, ple1, ple2, pln1, pln2);
    k_fuse1<<<2015, 384, 0, stream>>>(nodes, edges, pan1, ban1, pae1, bae1, H1n, H1e);
    k_fuse2<<<4030, 256, 0, stream>>>(H1n, pan2, ban2, hn, H1e, pae2, bae2, he);
    k_fuse3<<<4096, 192, 0, stream>>>(hn, nodes, pln1, bln1, pln2, bln2, out_nodes,
                                      he, edges, ein);
    k_le12<<<2015, 192, 0, stream>>>(ein, ple1, ble1, ple2, ble2, out_edges);

    (void)in_sizes; (void)n_in; (void)out_size; (void)ws_size;
}